// Round 8
// baseline (53.768 us; speedup 1.0000x reference)
//
#include <hip/hip_runtime.h>

// Depthwise temporal FIR (FW=64, SAME pad low=31/high=32), weight-norm +
// positivity clamp + bias.  out[t,c] = b[c] + sum_f relu(w[f,c]/||w[:,c]||) x[t-31+f,c]
//
// Round 6/7 post-mortem: 64 taps/thread forces live set wf[64]+xbuf[64]+ovh
// ~150 regs -> allocator spills ~4k movs/wave to AGPR regardless of
// launch_bounds (VGPR=84, 8.9k instr/wave vs 4.5k real). Round-8 fix: split
// taps across lane pairs (L: taps 0-31, L+32: taps 32-63). Live set ~90 VGPR,
// no spills. Per-step combine: one __shfl_xor(p,32). Windows per half are
// shifted by 32 (base_h = t0-31+32h, base_h % 32 == 1 for both halves), so
// the circular buffer xbuf[32] keeps compile-time slot indices (t0 % 32 == 0).

#define T_DIM 4096
#define C_DIM 4096
#define PAD_L 31
#define KTILE 64     // outputs per lane-pair (time tile)
#define HT    32     // taps per lane (half filter)
#define GRP   4      // prefetch batch depth

template <bool GUARD>
__device__ __forceinline__ void fir_body(const float* __restrict__ x,
                                         const float* __restrict__ w,
                                         const float* __restrict__ b,
                                         float* __restrict__ out,
                                         int c, int half, int t0) {
    const float* __restrict__ xp = x + c;                  // column base
    const float* __restrict__ wp = w + half * HT * C_DIM + c;
    float* __restrict__ op = out + (long long)t0 * C_DIM + c;

    // ---- weight-norm: partial sum-of-squares per half, combine via shfl ----
    float wf[HT];
    float ss = 0.0f;
#pragma unroll
    for (int j = 0; j < HT; ++j) {
        wf[j] = wp[j * C_DIM];
        ss = fmaf(wf[j], wf[j], ss);
    }
    ss += __shfl_xor(ss, 32);                              // full 64-tap norm
    const float inv = 1.0f / fmaxf(sqrtf(ss), 1e-8f);
#pragma unroll
    for (int j = 0; j < HT; ++j) wf[j] = fmaxf(wf[j] * inv, 0.0f);

    // bias contributed exactly once per output (by half 0)
    const float bvseed = (half == 0) ? b[c] : 0.0f;

    // this half's input window base: out[t] taps x[base+k .. base+k+31], k=t-t0
    const int base = t0 - PAD_L + HT * half;               // base % 32 == 1

    // ---- warm-up: xbuf[(base+i) & 31] = x[base+i], (base+i)&31 == (1+i)&31 ----
    float xbuf[HT];
#pragma unroll
    for (int i = 0; i < HT; ++i) {
        const int m = base + i;
        float v = 0.0f;
        if (!GUARD || ((unsigned)m < (unsigned)T_DIM))
            v = xp[(long long)m * C_DIM];
        xbuf[(1 + i) & 31] = v;
    }

    float xnA[GRP], xnB[GRP];

    // batch-load the next-window values consumed by group g's steps
#define PREFETCH(dst, g)                                                      \
    _Pragma("unroll")                                                         \
    for (int i = 0; i < GRP; ++i) {                                           \
        const int k = (g) * GRP + i;                                          \
        const int m = base + k + HT;                                          \
        float v = 0.0f;                                                       \
        if (k < KTILE - 1 && (!GUARD || ((unsigned)m < (unsigned)T_DIM)))     \
            v = xp[(long long)m * C_DIM];                                     \
        dst[i] = v;                                                           \
    }

    // one output step; k is a compile-time constant expression
#define FIR_STEP(k, src)                                                      \
    {                                                                         \
        float a0 = bvseed, a1 = 0.0f, a2 = 0.0f, a3 = 0.0f;                   \
        _Pragma("unroll")                                                     \
        for (int j = 0; j < HT; j += 4) {                                     \
            a0 = fmaf(wf[j + 0], xbuf[((k) + j + 1) & 31], a0);               \
            a1 = fmaf(wf[j + 1], xbuf[((k) + j + 2) & 31], a1);               \
            a2 = fmaf(wf[j + 2], xbuf[((k) + j + 3) & 31], a2);               \
            a3 = fmaf(wf[j + 3], xbuf[((k) + j + 4) & 31], a3);               \
        }                                                                     \
        float p = (a0 + a1) + (a2 + a3);                                      \
        p += __shfl_xor(p, 32);            /* full sum on both halves */      \
        if (half == ((k) & 1))             /* alternate halves store  */      \
            __builtin_nontemporal_store(p, op + (long long)(k) * C_DIM);      \
        if ((k) < KTILE - 1) xbuf[((k) + 1) & 31] = src[(k) & (GRP - 1)];     \
    }

#define GROUP(g, src)                                                         \
    FIR_STEP((g) * GRP + 0, src) FIR_STEP((g) * GRP + 1, src)                 \
    FIR_STEP((g) * GRP + 2, src) FIR_STEP((g) * GRP + 3, src)

    // software pipeline: prefetch group g+1 before computing group g
    PREFETCH(xnA, 0)
    PREFETCH(xnB, 1)  GROUP(0,  xnA)
    PREFETCH(xnA, 2)  GROUP(1,  xnB)
    PREFETCH(xnB, 3)  GROUP(2,  xnA)
    PREFETCH(xnA, 4)  GROUP(3,  xnB)
    PREFETCH(xnB, 5)  GROUP(4,  xnA)
    PREFETCH(xnA, 6)  GROUP(5,  xnB)
    PREFETCH(xnB, 7)  GROUP(6,  xnA)
    PREFETCH(xnA, 8)  GROUP(7,  xnB)
    PREFETCH(xnB, 9)  GROUP(8,  xnA)
    PREFETCH(xnA, 10) GROUP(9,  xnB)
    PREFETCH(xnB, 11) GROUP(10, xnA)
    PREFETCH(xnA, 12) GROUP(11, xnB)
    PREFETCH(xnB, 13) GROUP(12, xnA)
    PREFETCH(xnA, 14) GROUP(13, xnB)
    PREFETCH(xnB, 15) GROUP(14, xnA)
    GROUP(15, xnB)

#undef GROUP
#undef FIR_STEP
#undef PREFETCH
}

__global__ __launch_bounds__(256, 4) void depthwise_fir_kernel(
    const float* __restrict__ x, const float* __restrict__ w,
    const float* __restrict__ b, float* __restrict__ out) {
    const int lane = threadIdx.x & 63;
    const int wave = threadIdx.x >> 6;
    // lanes 0-31 and 32-63 of a wave cover the SAME 32 channels, halves 0/1
    const int c    = blockIdx.y * 128 + wave * 32 + (lane & 31);
    const int half = lane >> 5;
    const int t0   = blockIdx.x * KTILE;
    // zero-pad guard only at first/last time tile (block-uniform branch)
    if (blockIdx.x == 0 || blockIdx.x == gridDim.x - 1)
        fir_body<true>(x, w, b, out, c, half, t0);
    else
        fir_body<false>(x, w, b, out, c, half, t0);
}

extern "C" void kernel_launch(void* const* d_in, const int* in_sizes, int n_in,
                              void* d_out, int out_size, void* d_ws, size_t ws_size,
                              hipStream_t stream) {
    const float* x = (const float*)d_in[0];   // [T, C]
    const float* w = (const float*)d_in[1];   // [FW, C]
    const float* b = (const float*)d_in[2];   // [C]
    float* out = (float*)d_out;               // [T, C]

    dim3 grid(T_DIM / KTILE, C_DIM / 128);    // 64 x 32 blocks
    dim3 block(256);
    hipLaunchKernelGGL(depthwise_fir_kernel, grid, block, 0, stream, x, w, b, out);
}

// Round 9
// 50.377 us; speedup vs baseline: 1.0673x; 1.0673x over previous
//
#include <hip/hip_runtime.h>

// Depthwise temporal FIR (FW=64, SAME pad low=31/high=32), weight-norm +
// positivity clamp + bias. out[t,c] = b[c] + sum_f relu(w[f,c]/||w[:,c]||) x[t-31+f,c]
//
// Structure: lane-pair tap split (lanes L / L+32 = taps 0-31 / 32-63 of the
// same channel), 32-slot circular register window (period 32 -> all slot
// indices compile-time), RUNTIME loop over 4 periods of 32 steps (KTILE=128).
// Rounds 6-8 showed the fully-unrolled body drives the allocator to squeeze
// VGPRs (48..120) and emit ~2x spill movs; the period loop bounds live ranges
// and amdgpu_waves_per_eu(3,4) removes the incentive to squeeze below 128.
// Divergence-free epilogue: even/odd partials exchanged crosswise with one
// __shfl_xor(32); half0 stores even k, half1 odd k (one store per 2 outputs).

#define T_DIM 4096
#define C_DIM 4096
#define PAD_L 31
#define HT    32      // taps per lane (half filter)
#define KTILE 128     // outputs per lane-pair (time tile)
#define NPER  (KTILE / 32)

template <bool GUARD>
__device__ __forceinline__ void fir_body(const float* __restrict__ x,
                                         const float* __restrict__ w,
                                         const float* __restrict__ b,
                                         float* __restrict__ out,
                                         int c, int half, int t0) {
    const float* __restrict__ xp = x + c;                      // column base
    const float* __restrict__ wp = w + half * HT * C_DIM + c;
    // this lane stores outputs t0 + k + half (k even): fold +half into the base
    float* __restrict__ opl = out + ((long long)t0 + half) * C_DIM + c;

    // ---- weight-norm: per-half sum of squares, combined across the pair ----
    float wf[HT];
    float ss = 0.0f;
#pragma unroll
    for (int j = 0; j < HT; ++j) {
        wf[j] = wp[j * C_DIM];
        ss = fmaf(wf[j], wf[j], ss);
    }
    ss += __shfl_xor(ss, 32);                                  // full 64-tap norm
    const float inv = 1.0f / fmaxf(sqrtf(ss), 1e-8f);
#pragma unroll
    for (int j = 0; j < HT; ++j) wf[j] = fmaxf(wf[j] * inv, 0.0f);

    const float bv = b[c];
    const float se = (half == 0) ? bv : 0.0f;  // seed of the partial this lane STORES (even k)
    const float so = (half == 0) ? 0.0f : bv;  // seed of the odd-k partial (stored by half1)

    // window base: out[t0+k] uses x[base+k .. base+k+31]; base % 32 == 1
    const int base = t0 - PAD_L + HT * half;

    // ---- warm-up: xbuf[(base+i) & 31] = x[base+i]; (base+i)&31 == (1+i)&31 ----
    float xbuf[HT];
#pragma unroll
    for (int i = 0; i < HT; ++i) {
        const int m = base + i;
        float v = 0.0f;
        if (!GUARD || ((unsigned)m < (unsigned)T_DIM)) v = xp[(long long)m * C_DIM];
        xbuf[(1 + i) & 31] = v;
    }

    // ---- prefetch buffers: values consumed during the CURRENT period ----
    // step kk of period p consumes m = base + 32 + p*32 + kk (inserted after use of oldest)
    float pfA[16], pfB[16];
#pragma unroll
    for (int i = 0; i < 16; ++i) {
        const int m = base + 32 + i;
        float v = 0.0f;
        if (!GUARD || ((unsigned)m < (unsigned)T_DIM)) v = xp[(long long)m * C_DIM];
        pfA[i] = v;
    }
#pragma unroll
    for (int i = 0; i < 16; ++i) {
        const int m = base + 48 + i;
        float v = 0.0f;
        if (!GUARD || ((unsigned)m < (unsigned)T_DIM)) v = xp[(long long)m * C_DIM];
        pfB[i] = v;
    }

    // 32-tap partial for step kk (compile-time kk -> static xbuf slots)
#define PARTIAL(kk, seed, dst)                                                \
    float dst;                                                                \
    {                                                                         \
        float a0 = (seed), a1 = 0.0f;                                         \
        _Pragma("unroll")                                                     \
        for (int j = 0; j < HT; j += 2) {                                     \
            a0 = fmaf(wf[j],     xbuf[((kk) + j + 1) & 31], a0);              \
            a1 = fmaf(wf[j + 1], xbuf[((kk) + j + 2) & 31], a1);              \
        }                                                                     \
        dst = a0 + a1;                                                        \
    }

    // two steps (even kk, kk+1), crosswise exchange, one store per lane-pair half
#define STEP_PAIR(kk)                                                         \
    {                                                                         \
        PARTIAL(kk, se, pe)                                                   \
        xbuf[((kk) + 1) & 31] = ((kk) < 16) ? pfA[(kk) & 15] : pfB[(kk) & 15];\
        PARTIAL((kk) + 1, so, po)                                             \
        xbuf[((kk) + 2) & 31] =                                               \
            (((kk) + 1) < 16) ? pfA[((kk) + 1) & 15] : pfB[((kk) + 1) & 15];  \
        const float snd = (half == 0) ? po : pe;                              \
        const float rcv = __shfl_xor(snd, 32);                                \
        const float res = ((half == 0) ? pe : po) + rcv;                      \
        __builtin_nontemporal_store(res, opl + (long long)(kb + (kk)) * C_DIM);\
    }

#pragma unroll 1
    for (int p = 0; p < NPER; ++p) {
        const int kb = p * 32;
        STEP_PAIR(0)  STEP_PAIR(2)  STEP_PAIR(4)  STEP_PAIR(6)
        STEP_PAIR(8)  STEP_PAIR(10) STEP_PAIR(12) STEP_PAIR(14)
        if (p < NPER - 1) {            // refill pfA for next period (uniform branch)
#pragma unroll
            for (int i = 0; i < 16; ++i) {
                const int m = base + 64 + kb + i;
                float v = 0.0f;
                if (!GUARD || ((unsigned)m < (unsigned)T_DIM)) v = xp[(long long)m * C_DIM];
                pfA[i] = v;
            }
        }
        STEP_PAIR(16) STEP_PAIR(18) STEP_PAIR(20) STEP_PAIR(22)
        STEP_PAIR(24) STEP_PAIR(26) STEP_PAIR(28) STEP_PAIR(30)
        if (p < NPER - 1) {            // refill pfB for next period
#pragma unroll
            for (int i = 0; i < 16; ++i) {
                const int m = base + 80 + kb + i;
                float v = 0.0f;
                if (!GUARD || ((unsigned)m < (unsigned)T_DIM)) v = xp[(long long)m * C_DIM];
                pfB[i] = v;
            }
        }
    }

#undef STEP_PAIR
#undef PARTIAL
}

__global__ __launch_bounds__(256)
__attribute__((amdgpu_waves_per_eu(3, 4)))
void depthwise_fir_kernel(const float* __restrict__ x, const float* __restrict__ w,
                          const float* __restrict__ b, float* __restrict__ out) {
    const int lane = threadIdx.x & 63;
    const int wave = threadIdx.x >> 6;
    // lanes 0-31 / 32-63 of a wave: same 32 channels, tap-halves 0 / 1
    const int c    = blockIdx.y * 128 + wave * 32 + (lane & 31);
    const int half = lane >> 5;
    const int t0   = blockIdx.x * KTILE;
    // zero-pad guard only at first/last time tile (block-uniform branch)
    if (blockIdx.x == 0 || blockIdx.x == gridDim.x - 1)
        fir_body<true>(x, w, b, out, c, half, t0);
    else
        fir_body<false>(x, w, b, out, c, half, t0);
}

extern "C" void kernel_launch(void* const* d_in, const int* in_sizes, int n_in,
                              void* d_out, int out_size, void* d_ws, size_t ws_size,
                              hipStream_t stream) {
    const float* x = (const float*)d_in[0];   // [T, C]
    const float* w = (const float*)d_in[1];   // [FW, C]
    const float* b = (const float*)d_in[2];   // [C]
    float* out = (float*)d_out;               // [T, C]

    dim3 grid(T_DIM / KTILE, C_DIM / 128);    // 32 x 32 = 1024 blocks = 4/CU
    dim3 block(256);
    hipLaunchKernelGGL(depthwise_fir_kernel, grid, block, 0, stream, x, w, b, out);
}